// Round 7
// baseline (54.179 us; speedup 1.0000x reference)
//
#include <hip/hip_runtime.h>
#include <math.h>

#define NPART 8
#define NN    128   // neighbors per batch

typedef float f32x4 __attribute__((ext_vector_type(4)));

// ---------------- K1: features + social_circle ----------------
// One WAVE per batch (best geometry so far). 4 waves/block, per-wave private
// LDS bins, no __syncthreads. Lane l handles neighbors l and l+64.
// Reads 134MB, writes only scout (1.6MB) -> pure read-stream kernel.
__global__ __launch_bounds__(256) void sc_kernel(
    const float* __restrict__ nei,   // (B, 128, 8, 2) f32
    float* __restrict__ scout,       // (B, 8, 3) f32
    int Btot)
{
    const int tid  = threadIdx.x;
    const int lane = tid & 63;
    const int wv   = tid >> 6;
    const int b    = blockIdx.x * 4 + wv;
    if (b >= Btot) return;

    __shared__ float s_sum[4][NPART * 3];
    __shared__ float s_cnt[4][NPART];

    // ---- issue all 8 input loads first ----
    const f32x4* src = reinterpret_cast<const f32x4*>(nei) + (size_t)b * (NN * 4);
    f32x4 a0 = src[lane * 4 + 0];
    f32x4 c0 = src[lane * 4 + 1];
    f32x4 d0 = src[lane * 4 + 2];
    f32x4 e0 = src[lane * 4 + 3];
    f32x4 a1 = src[256 + lane * 4 + 0];
    f32x4 c1 = src[256 + lane * 4 + 1];
    f32x4 d1 = src[256 + lane * 4 + 2];
    f32x4 e1 = src[256 + lane * 4 + 3];

    if (lane < NPART * 3) s_sum[wv][lane] = 0.0f;
    if (lane < NPART)     s_cnt[wv][lane] = 0.0f;
    __builtin_amdgcn_wave_barrier();

    const float TWOPI = 6.2831853071795864769f;
    const float STEP  = (float)(6.283185307179586 / 8.0);

    #pragma unroll
    for (int h = 0; h < 2; ++h) {
        f32x4 a = h ? a1 : a0;
        f32x4 c = h ? c1 : c0;
        f32x4 d = h ? d1 : d0;
        f32x4 e = h ? e1 : e0;

        float total = (((a.x + a.y) + (a.z + a.w)) + ((c.x + c.y) + (c.z + c.w)))
                    + (((d.x + d.y) + (d.z + d.w)) + ((e.x + e.y) + (e.z + e.w)));

        float px = e.z, py = e.w;            // last position (t7)
        float vx = px - a.x, vy = py - a.y;  // last - first
        float fvel  = sqrtf(vx * vx + vy * vy);
        float fdist = sqrtf(px * px + py * py);

        float fdir = atan2f(px, py);
        if (fdir < 0.0f) fdir += TWOPI;

        int idx = (int)(fdir / STEP);

        if (total != 0.0f && idx >= 0 && idx < NPART) {
            atomicAdd(&s_sum[wv][idx * 3 + 0], fvel);
            atomicAdd(&s_sum[wv][idx * 3 + 1], fdist);
            atomicAdd(&s_sum[wv][idx * 3 + 2], fdir);
            atomicAdd(&s_cnt[wv][idx], 1.0f);
        }
    }
    __builtin_amdgcn_wave_barrier();

    // ---- finalize social_circle (lanes 0..23), write output 2 ----
    if (lane < NPART * 3) {
        float v = s_sum[wv][lane] / (s_cnt[wv][lane / 3] + 0.0001f);
        scout[(size_t)b * (NPART * 3) + lane] = v;
    }
}

// ---------------- K2: f_sc = relu(sc @ W + b) ----------------
// Thread -> fixed (partition p = tid>>5, columns 4*(tid&31)..+3).
// Block handles 8 consecutive batches; all 8 sc-triples loaded up front
// (independent -> pipelined), then 8x {12 FMA + relu + float4 store}.
// Pure write-stream kernel (67MB), reads are tiny and L2/L3-hot.
__global__ __launch_bounds__(256) void fsc_kernel(
    const float* __restrict__ sc,    // (B, 8, 3) f32
    const float* __restrict__ W,     // (3, 128) f32
    const float* __restrict__ bce,   // (128,) f32
    float* __restrict__ fsc,         // (B, 8, 128) f32
    int Btot)
{
    const int tid = threadIdx.x;
    const int p   = tid >> 5;           // partition 0..7
    const int c0i = (tid & 31) * 4;     // column group

    f32x4 wr0 = *reinterpret_cast<const f32x4*>(W + 0 * NN + c0i);
    f32x4 wr1 = *reinterpret_cast<const f32x4*>(W + 1 * NN + c0i);
    f32x4 wr2 = *reinterpret_cast<const f32x4*>(W + 2 * NN + c0i);
    f32x4 bb  = *reinterpret_cast<const f32x4*>(bce + c0i);

    const int base = blockIdx.x * 8;

    float sv[8], sd[8], sr[8];
    #pragma unroll
    for (int i = 0; i < 8; ++i) {
        int b = base + i;
        if (b < Btot) {
            const float* s = sc + (size_t)b * (NPART * 3) + p * 3;
            sv[i] = s[0];
            sd[i] = s[1];
            sr[i] = s[2];
        }
    }

    #pragma unroll
    for (int i = 0; i < 8; ++i) {
        int b = base + i;
        if (b < Btot) {
            f32x4 acc;
            acc.x = fmaxf(fmaf(sv[i], wr0.x, fmaf(sd[i], wr1.x, fmaf(sr[i], wr2.x, bb.x))), 0.0f);
            acc.y = fmaxf(fmaf(sv[i], wr0.y, fmaf(sd[i], wr1.y, fmaf(sr[i], wr2.y, bb.y))), 0.0f);
            acc.z = fmaxf(fmaf(sv[i], wr0.z, fmaf(sd[i], wr1.z, fmaf(sr[i], wr2.z, bb.z))), 0.0f);
            acc.w = fmaxf(fmaf(sv[i], wr0.w, fmaf(sd[i], wr1.w, fmaf(sr[i], wr2.w, bb.w))), 0.0f);
            *reinterpret_cast<f32x4*>(fsc + (size_t)b * NPART * NN + p * NN + c0i) = acc;
        }
    }
}

extern "C" void kernel_launch(void* const* d_in, const int* in_sizes, int n_in,
                              void* d_out, int out_size, void* d_ws, size_t ws_size,
                              hipStream_t stream) {
    // inputs: 0=trajs (UNUSED by reference), 1=nei_trajs, 2=W_ce, 3=b_ce
    const float* nei = (const float*)d_in[1];
    const float* W   = (const float*)d_in[2];
    const float* bce = (const float*)d_in[3];

    const int Btot = in_sizes[1] / (NN * 8 * 2);   // 16384

    // outputs concatenated: f_sc (B,8,128) then social_circle (B,8,3)
    float* fsc   = (float*)d_out;
    float* scout = fsc + (size_t)Btot * NPART * NN;

    sc_kernel<<<(Btot + 3) / 4, 256, 0, stream>>>(nei, scout, Btot);
    fsc_kernel<<<(Btot + 7) / 8, 256, 0, stream>>>(scout, W, bce, fsc, Btot);
}

// Round 8
// 44.297 us; speedup vs baseline: 1.2231x; 1.2231x over previous
//
#include <hip/hip_runtime.h>
#include <math.h>

#define NPART 8
#define NN    128   // neighbors per batch

typedef float f32x4 __attribute__((ext_vector_type(4)));

// atan2(y,x) folded directly into [0, 2pi) (matches arctan2(y,x) % 2pi).
// Octant fold + cephes-style poly on [0, tan(pi/8)]; divisions via v_rcp +
// one Newton step (~1 ulp). Max abs err ~1.5e-7 rad — same scale as libm
// atan2f vs the numpy reference, so near-boundary bin-flip risk unchanged.
__device__ __forceinline__ float atan2_2pi(float y, float x) {
    const float PI_F    = 3.14159265358979f;
    const float PIO2_F  = 1.57079632679490f;
    const float PIO4_F  = 0.78539816339745f;
    const float TWOPI_F = 6.28318530717959f;
    float ay = fabsf(y), ax = fabsf(x);
    float mn = fminf(ay, ax), mx = fmaxf(ay, ax);
    float r  = __builtin_amdgcn_rcpf(mx);
    float q  = mn * r;
    q = fmaf(fmaf(-mx, q, mn), r, q);            // q = mn/mx in [0,1]
    bool  big  = q > 0.41421356237f;             // tan(pi/8)
    float num2 = q - 1.0f, den2 = q + 1.0f;
    float r2   = __builtin_amdgcn_rcpf(den2);
    float q2   = num2 * r2;
    q2 = fmaf(fmaf(-den2, q2, num2), r2, q2);    // (q-1)/(q+1) in [-.414,0]
    float t = big ? q2 : q;
    float u = t * t;
    float p = fmaf(u, 8.05374449538e-2f, -1.38776856032e-1f);
    p = fmaf(u, p, 1.99777106478e-1f);
    p = fmaf(u, p, -3.33329491539e-1f);
    float z0 = fmaf(p * u, t, t);
    if (big) z0 += PIO4_F;                       // atan(mn/mx) in [0, pi/4]
    float zq = (ay > ax) ? (PIO2_F - z0) : z0;   // [0, pi/2]
    float z1 = (x < 0.0f) ? (PI_F - zq) : zq;
    return (y < 0.0f) ? (TWOPI_F - z1) : z1;     // [0, 2pi)
}

// One WAVE per batch (R3 geometry — best). 4 waves/block, per-wave private
// LDS bins SPLIT per half-wave (halves same-address atomic serialization),
// no __syncthreads. Lane l handles neighbors l and l+64. Weights loaded
// AFTER the feature phase to cut peak VGPR (<=64 -> 8 waves/SIMD).
__global__ __launch_bounds__(256) void sc_kernel(
    const float* __restrict__ nei,   // (B, 128, 8, 2) f32
    const float* __restrict__ W,     // (3, 128) f32
    const float* __restrict__ bce,   // (128,) f32
    float* __restrict__ fsc,         // (B, 8, 128) f32
    float* __restrict__ scout,       // (B, 8, 3) f32
    int Btot)
{
    const int tid  = threadIdx.x;
    const int lane = tid & 63;
    const int wv   = tid >> 6;
    const int hi   = lane >> 5;
    const int b    = blockIdx.x * 4 + wv;
    if (b >= Btot) return;

    __shared__ float s_sum[4][2][NPART * 3];
    __shared__ float s_cnt[4][2][NPART];
    __shared__ float s_sc[4][NPART * 3];

    // ---- issue all 8 input loads first ----
    const f32x4* src = reinterpret_cast<const f32x4*>(nei) + (size_t)b * (NN * 4);
    f32x4 a0 = src[lane * 4 + 0];
    f32x4 c0 = src[lane * 4 + 1];
    f32x4 d0 = src[lane * 4 + 2];
    f32x4 e0 = src[lane * 4 + 3];
    f32x4 a1 = src[256 + lane * 4 + 0];
    f32x4 c1 = src[256 + lane * 4 + 1];
    f32x4 d1 = src[256 + lane * 4 + 2];
    f32x4 e1 = src[256 + lane * 4 + 3];

    // bin init: half-lanes 0-23 zero sums, 24-31 zero counts (both copies)
    {
        int ll = lane & 31;
        if (ll < NPART * 3) s_sum[wv][hi][ll] = 0.0f;
        else                s_cnt[wv][hi][ll - NPART * 3] = 0.0f;
    }
    __builtin_amdgcn_wave_barrier();

    #pragma unroll
    for (int h = 0; h < 2; ++h) {
        f32x4 a = h ? a1 : a0;
        f32x4 c = h ? c1 : c0;
        f32x4 d = h ? d1 : d0;
        f32x4 e = h ? e1 : e0;

        float total = (((a.x + a.y) + (a.z + a.w)) + ((c.x + c.y) + (c.z + c.w)))
                    + (((d.x + d.y) + (d.z + d.w)) + ((e.x + e.y) + (e.z + e.w)));

        float px = e.z, py = e.w;            // last position (t7)
        float vx = px - a.x, vy = py - a.y;  // last - first
        float fvel  = sqrtf(vx * vx + vy * vy);
        float fdist = sqrtf(px * px + py * py);

        float fdir = atan2_2pi(px, py);
        int idx = (int)(fdir * 1.27323954474f);   // * 4/pi == / (2pi/8)

        if (total != 0.0f && idx >= 0 && idx < NPART) {
            atomicAdd(&s_sum[wv][hi][idx * 3 + 0], fvel);
            atomicAdd(&s_sum[wv][hi][idx * 3 + 1], fdist);
            atomicAdd(&s_sum[wv][hi][idx * 3 + 2], fdir);
            atomicAdd(&s_cnt[wv][hi][idx], 1.0f);
        }
    }
    __builtin_amdgcn_wave_barrier();

    // ---- finalize social_circle (lanes 0..23): merge copies, write out 2 ----
    if (lane < NPART * 3) {
        float v = (s_sum[wv][0][lane] + s_sum[wv][1][lane]) /
                  (s_cnt[wv][0][lane / 3] + s_cnt[wv][1][lane / 3] + 0.0001f);
        s_sc[wv][lane] = v;
        scout[(size_t)b * (NPART * 3) + lane] = v;
    }
    __builtin_amdgcn_wave_barrier();

    // ---- epilogue: f_sc = relu(sc @ W + b); weights loaded LATE (L1-hot) ----
    const int c0i = 4 * (lane & 31);
    f32x4 wr0 = *reinterpret_cast<const f32x4*>(W + 0 * NN + c0i);
    f32x4 wr1 = *reinterpret_cast<const f32x4*>(W + 1 * NN + c0i);
    f32x4 wr2 = *reinterpret_cast<const f32x4*>(W + 2 * NN + c0i);
    f32x4 bb  = *reinterpret_cast<const f32x4*>(bce + c0i);

    float* o = fsc + (size_t)b * NPART * NN;
    #pragma unroll
    for (int s = 0; s < 4; ++s) {
        int p = 2 * s + hi;
        float sv = s_sc[wv][p * 3 + 0];   // 2-address broadcast: conflict-free
        float sd = s_sc[wv][p * 3 + 1];
        float sr = s_sc[wv][p * 3 + 2];
        f32x4 acc;
        acc.x = fmaxf(fmaf(sv, wr0.x, fmaf(sd, wr1.x, fmaf(sr, wr2.x, bb.x))), 0.0f);
        acc.y = fmaxf(fmaf(sv, wr0.y, fmaf(sd, wr1.y, fmaf(sr, wr2.y, bb.y))), 0.0f);
        acc.z = fmaxf(fmaf(sv, wr0.z, fmaf(sd, wr1.z, fmaf(sr, wr2.z, bb.z))), 0.0f);
        acc.w = fmaxf(fmaf(sv, wr0.w, fmaf(sd, wr1.w, fmaf(sr, wr2.w, bb.w))), 0.0f);
        *reinterpret_cast<f32x4*>(o + p * NN + c0i) = acc;
    }
}

extern "C" void kernel_launch(void* const* d_in, const int* in_sizes, int n_in,
                              void* d_out, int out_size, void* d_ws, size_t ws_size,
                              hipStream_t stream) {
    // inputs: 0=trajs (UNUSED by reference), 1=nei_trajs, 2=W_ce, 3=b_ce
    const float* nei = (const float*)d_in[1];
    const float* W   = (const float*)d_in[2];
    const float* bce = (const float*)d_in[3];

    const int Btot = in_sizes[1] / (NN * 8 * 2);   // 16384

    // outputs concatenated: f_sc (B,8,128) then social_circle (B,8,3)
    float* fsc   = (float*)d_out;
    float* scout = fsc + (size_t)Btot * NPART * NN;

    sc_kernel<<<(Btot + 3) / 4, 256, 0, stream>>>(nei, W, bce, fsc, scout, Btot);
}

// Round 9
// 42.647 us; speedup vs baseline: 1.2704x; 1.0387x over previous
//
#include <hip/hip_runtime.h>
#include <math.h>

#define NPART 8
#define NN    128   // neighbors per batch

typedef float f32x4 __attribute__((ext_vector_type(4)));

// atan2(y,x) folded directly into [0, 2pi) (matches arctan2(y,x) % 2pi).
// Octant fold + cephes-style poly on [0, tan(pi/8)]; divisions via v_rcp +
// one Newton step (~1 ulp). Max abs err ~1.5e-7 rad.
__device__ __forceinline__ float atan2_2pi(float y, float x) {
    const float PI_F    = 3.14159265358979f;
    const float PIO2_F  = 1.57079632679490f;
    const float PIO4_F  = 0.78539816339745f;
    const float TWOPI_F = 6.28318530717959f;
    float ay = fabsf(y), ax = fabsf(x);
    float mn = fminf(ay, ax), mx = fmaxf(ay, ax);
    float r  = __builtin_amdgcn_rcpf(mx);
    float q  = mn * r;
    q = fmaf(fmaf(-mx, q, mn), r, q);            // q = mn/mx in [0,1]
    bool  big  = q > 0.41421356237f;             // tan(pi/8)
    float num2 = q - 1.0f, den2 = q + 1.0f;
    float r2   = __builtin_amdgcn_rcpf(den2);
    float q2   = num2 * r2;
    q2 = fmaf(fmaf(-den2, q2, num2), r2, q2);    // (q-1)/(q+1) in [-.414,0]
    float t = big ? q2 : q;
    float u = t * t;
    float p = fmaf(u, 8.05374449538e-2f, -1.38776856032e-1f);
    p = fmaf(u, p, 1.99777106478e-1f);
    p = fmaf(u, p, -3.33329491539e-1f);
    float z0 = fmaf(p * u, t, t);
    if (big) z0 += PIO4_F;                       // atan(mn/mx) in [0, pi/4]
    float zq = (ay > ax) ? (PIO2_F - z0) : z0;   // [0, pi/2]
    float z1 = (x < 0.0f) ? (PI_F - zq) : zq;
    return (y < 0.0f) ? (TWOPI_F - z1) : z1;     // [0, 2pi)
}

// One WAVE per batch (R3 geometry — best). 4 waves/block, per-wave private
// LDS bins split per half-wave, no __syncthreads. Lane l handles neighbors
// l and l+64. LOADS cacheable (input is L3-resident across replays, worth
// ~66MB of HBM); output STORES nontemporal (never re-read — keep the 67MB
// write stream from write-allocating L2/L3 and evicting the input).
__global__ __launch_bounds__(256) void sc_kernel(
    const float* __restrict__ nei,   // (B, 128, 8, 2) f32
    const float* __restrict__ W,     // (3, 128) f32
    const float* __restrict__ bce,   // (128,) f32
    float* __restrict__ fsc,         // (B, 8, 128) f32
    float* __restrict__ scout,       // (B, 8, 3) f32
    int Btot)
{
    const int tid  = threadIdx.x;
    const int lane = tid & 63;
    const int wv   = tid >> 6;
    const int hi   = lane >> 5;
    const int b    = blockIdx.x * 4 + wv;
    if (b >= Btot) return;

    __shared__ float s_sum[4][2][NPART * 3];
    __shared__ float s_cnt[4][2][NPART];
    __shared__ float s_sc[4][NPART * 3];

    // ---- issue all 8 input loads first (cacheable) ----
    const f32x4* src = reinterpret_cast<const f32x4*>(nei) + (size_t)b * (NN * 4);
    f32x4 a0 = src[lane * 4 + 0];
    f32x4 c0 = src[lane * 4 + 1];
    f32x4 d0 = src[lane * 4 + 2];
    f32x4 e0 = src[lane * 4 + 3];
    f32x4 a1 = src[256 + lane * 4 + 0];
    f32x4 c1 = src[256 + lane * 4 + 1];
    f32x4 d1 = src[256 + lane * 4 + 2];
    f32x4 e1 = src[256 + lane * 4 + 3];

    // bin init: half-lanes 0-23 zero sums, 24-31 zero counts (both copies)
    {
        int ll = lane & 31;
        if (ll < NPART * 3) s_sum[wv][hi][ll] = 0.0f;
        else                s_cnt[wv][hi][ll - NPART * 3] = 0.0f;
    }
    __builtin_amdgcn_wave_barrier();

    #pragma unroll
    for (int h = 0; h < 2; ++h) {
        f32x4 a = h ? a1 : a0;
        f32x4 c = h ? c1 : c0;
        f32x4 d = h ? d1 : d0;
        f32x4 e = h ? e1 : e0;

        float total = (((a.x + a.y) + (a.z + a.w)) + ((c.x + c.y) + (c.z + c.w)))
                    + (((d.x + d.y) + (d.z + d.w)) + ((e.x + e.y) + (e.z + e.w)));

        float px = e.z, py = e.w;            // last position (t7)
        float vx = px - a.x, vy = py - a.y;  // last - first
        float fvel  = sqrtf(vx * vx + vy * vy);
        float fdist = sqrtf(px * px + py * py);

        float fdir = atan2_2pi(px, py);
        int idx = (int)(fdir * 1.27323954474f);   // * 4/pi == / (2pi/8)

        if (total != 0.0f && idx >= 0 && idx < NPART) {
            atomicAdd(&s_sum[wv][hi][idx * 3 + 0], fvel);
            atomicAdd(&s_sum[wv][hi][idx * 3 + 1], fdist);
            atomicAdd(&s_sum[wv][hi][idx * 3 + 2], fdir);
            atomicAdd(&s_cnt[wv][hi][idx], 1.0f);
        }
    }
    __builtin_amdgcn_wave_barrier();

    // ---- finalize social_circle (lanes 0..23): merge copies, write out 2 ----
    if (lane < NPART * 3) {
        float v = (s_sum[wv][0][lane] + s_sum[wv][1][lane]) /
                  (s_cnt[wv][0][lane / 3] + s_cnt[wv][1][lane / 3] + 0.0001f);
        s_sc[wv][lane] = v;
        __builtin_nontemporal_store(v, scout + (size_t)b * (NPART * 3) + lane);
    }
    __builtin_amdgcn_wave_barrier();

    // ---- epilogue: f_sc = relu(sc @ W + b); nontemporal float4 stores ----
    const int c0i = 4 * (lane & 31);
    f32x4 wr0 = *reinterpret_cast<const f32x4*>(W + 0 * NN + c0i);
    f32x4 wr1 = *reinterpret_cast<const f32x4*>(W + 1 * NN + c0i);
    f32x4 wr2 = *reinterpret_cast<const f32x4*>(W + 2 * NN + c0i);
    f32x4 bb  = *reinterpret_cast<const f32x4*>(bce + c0i);

    float* o = fsc + (size_t)b * NPART * NN;
    #pragma unroll
    for (int s = 0; s < 4; ++s) {
        int p = 2 * s + hi;
        float sv = s_sc[wv][p * 3 + 0];   // 2-address broadcast: conflict-free
        float sd = s_sc[wv][p * 3 + 1];
        float sr = s_sc[wv][p * 3 + 2];
        f32x4 acc;
        acc.x = fmaxf(fmaf(sv, wr0.x, fmaf(sd, wr1.x, fmaf(sr, wr2.x, bb.x))), 0.0f);
        acc.y = fmaxf(fmaf(sv, wr0.y, fmaf(sd, wr1.y, fmaf(sr, wr2.y, bb.y))), 0.0f);
        acc.z = fmaxf(fmaf(sv, wr0.z, fmaf(sd, wr1.z, fmaf(sr, wr2.z, bb.z))), 0.0f);
        acc.w = fmaxf(fmaf(sv, wr0.w, fmaf(sd, wr1.w, fmaf(sr, wr2.w, bb.w))), 0.0f);
        __builtin_nontemporal_store(acc, reinterpret_cast<f32x4*>(o + p * NN + c0i));
    }
}

extern "C" void kernel_launch(void* const* d_in, const int* in_sizes, int n_in,
                              void* d_out, int out_size, void* d_ws, size_t ws_size,
                              hipStream_t stream) {
    // inputs: 0=trajs (UNUSED by reference), 1=nei_trajs, 2=W_ce, 3=b_ce
    const float* nei = (const float*)d_in[1];
    const float* W   = (const float*)d_in[2];
    const float* bce = (const float*)d_in[3];

    const int Btot = in_sizes[1] / (NN * 8 * 2);   // 16384

    // outputs concatenated: f_sc (B,8,128) then social_circle (B,8,3)
    float* fsc   = (float*)d_out;
    float* scout = fsc + (size_t)Btot * NPART * NN;

    sc_kernel<<<(Btot + 3) / 4, 256, 0, stream>>>(nei, W, bce, fsc, scout, Btot);
}